// Round 3
// baseline (898.536 us; speedup 1.0000x reference)
//
#include <hip/hip_runtime.h>

typedef __bf16 bf16;
typedef __bf16 bf16x8 __attribute__((ext_vector_type(8)));
typedef __bf16 bf16x4 __attribute__((ext_vector_type(4)));
typedef float  f32x4  __attribute__((ext_vector_type(4)));

// Problem constants: FX=64, FU=64, f_in=192, H=256, FE_OUT=64
#define KDIM 192
#define HDIM 256
#define NOUT 64

// ---------------------------------------------------------------------------
// Prep: W1 [192][256] fp32 -> W1T [256][192] bf16 ; W2 [256][64] -> W2T [64][256]
// ---------------------------------------------------------------------------
__global__ __launch_bounds__(256) void prep_weights(
    const float* __restrict__ W1, const float* __restrict__ W2,
    bf16* __restrict__ W1T, bf16* __restrict__ W2T)
{
    int gid = blockIdx.x * 256 + threadIdx.x;
    if (gid < KDIM * HDIM) {                  // 49152 = W1T elements
        int n = gid / KDIM;                   // 0..255
        int k = gid - n * KDIM;               // 0..191
        W1T[gid] = (bf16)W1[k * HDIM + n];
    } else {
        int g2 = gid - KDIM * HDIM;           // 0..16383
        int n = g2 >> 8;                      // 0..63
        int k = g2 & 255;                     // 0..255
        W2T[g2] = (bf16)W2[k * NOUT + n];
    }
}

// ---------------------------------------------------------------------------
// Round-3: OCCUPANCY. Counters showed everything idle (Mfma 9%, VALU 9%,
// HBM 36%, Occ 22.5% = 2 waves/SIMD) across three rounds of access-pattern
// changes -> latency/sync-bound. Fix: overlay hs on xs (never live in the
// same phase) -> LDS 59392 -> 33792 B -> 4 blocks/CU = 16 waves/CU. Cost:
// 4 barriers/tile instead of 2, but 4 independent blocks per CU now cover
// each other's stalls. VGPR pinned <=128 via __launch_bounds__(256,4)
// (compiler already allocates exactly 128 for this structure).
// Barrier schedule per tile:
//   stage xs -> B1(xs ready) -> L1 MFMA -> B2(xs reads done, region free)
//   -> epi1 writes hs -> B3(hs ready) -> L2 MFMA + prefetch + epi2 + stores
//   -> B4(hs reads done, region free for next stage)
// ---------------------------------------------------------------------------
__global__ __launch_bounds__(256, 4) void edge_mlp(
    const float* __restrict__ srcf, const float* __restrict__ destf,
    const float* __restrict__ u,    const int* __restrict__ batch,
    const bf16* __restrict__ W1T,   const float* __restrict__ b1,
    const bf16* __restrict__ W2T,   const float* __restrict__ b2,
    float* __restrict__ out, int E)
{
    // one 33792-B region: xs[64][200]bf16 (25600 B) and hs[64][264]bf16
    // (33792 B) OVERLAY each other; outs[64][132]f32 row-aliases hs.
    __shared__ __align__(16) unsigned char smem[64 * 264 * 2];
    bf16  (*xs)[200]   = (bf16 (*)[200])smem;
    bf16  (*hs)[264]   = (bf16 (*)[264])smem;
    float (*outs)[132] = (float (*)[132])smem;   // 528-B rows == hs rows

    const int tid  = threadIdx.x;
    const int row  = tid >> 2;        // 0..63  (u-staging row)
    const int c0   = (tid & 3) * 16;  // 0..48  (u-staging col base)
    const int wave = tid >> 6;
    const int lane = tid & 63;
    const int q    = lane >> 4;       // quad 0..3
    const int cl   = lane & 15;       // 0..15

    // flat-remap staging coords: float4 #(j*256+tid) of the 64x64 f32 tile
    const int r0 = tid >> 4;          // row for j=0; j adds 16
    const int cp = tid & 15;          // float4 slot within row

    const int ntiles = (E + 63) >> 6;
    const int stride = gridDim.x;

    int it = blockIdx.x;
    if (it >= ntiles) return;

    const int wn0 = wave * 64;
    const int m0  = wave * 16;

    float bias1[4], bias2[4];
#pragma unroll
    for (int nt = 0; nt < 4; ++nt) {
        bias1[nt] = b1[wn0 + nt * 16 + cl];
        bias2[nt] = b2[nt * 16 + cl];
    }

    f32x4 dr[4], sr[4], ur[4];
    const f32x4 zero4 = {0.f, 0.f, 0.f, 0.f};

    // ---- preamble: tile(it) -> regs ----
    {
        const size_t tb = (size_t)it * 1024;   // tile base in float4 units
#pragma unroll
        for (int j = 0; j < 4; ++j) {
            const int g = j * 256 + tid;
            const int e = it * 64 + (g >> 4);
            if (e < E) {
                dr[j] = ((const f32x4*)destf)[tb + g];
                sr[j] = ((const f32x4*)srcf)[tb + g];
            } else { dr[j] = zero4; sr[j] = zero4; }
        }
        const int e = it * 64 + row;
        if (e < E) {
            const int b = batch[e];
            const f32x4* up = (const f32x4*)(u + (size_t)b * 64 + c0);
#pragma unroll
            for (int i = 0; i < 4; ++i) ur[i] = up[i];
        } else {
#pragma unroll
            for (int i = 0; i < 4; ++i) ur[i] = zero4;
        }
    }
    int itn = it + stride;
    int bn  = 0;
    if (itn < ntiles) {
        int en = itn * 64 + row;
        if (en < E) bn = batch[en];
    }

    while (true) {
        const int e0 = it * 64;

        // ---- stage xs from regs (fp32 -> bf16) ----
#pragma unroll
        for (int j = 0; j < 4; ++j) {
            const int r = j * 16 + r0;
            bf16x4 db = { (bf16)dr[j].x, (bf16)dr[j].y, (bf16)dr[j].z, (bf16)dr[j].w };
            bf16x4 sb = { (bf16)sr[j].x, (bf16)sr[j].y, (bf16)sr[j].z, (bf16)sr[j].w };
            *(bf16x4*)&xs[r][cp * 4]      = db;
            *(bf16x4*)&xs[r][64 + cp * 4] = sb;
        }
#pragma unroll
        for (int i = 0; i < 4; ++i) {
            bf16x4 ub = { (bf16)ur[i].x, (bf16)ur[i].y, (bf16)ur[i].z, (bf16)ur[i].w };
            *(bf16x4*)&xs[row][128 + c0 + i * 4] = ub;
        }

        __syncthreads();   // B1: xs ready

        // ---- layer 1: wave owns N cols [64w, 64w+64), all 64 M rows ----
        f32x4 acc[4][4] = {};
        const bf16* w1base = W1T + (size_t)wn0 * KDIM;
        __builtin_amdgcn_s_setprio(1);
#pragma unroll
        for (int ks = 0; ks < 6; ++ks) {
            const int k0 = ks * 32 + q * 8;
            bf16x8 a[4], bb[4];
#pragma unroll
            for (int mt = 0; mt < 4; ++mt)
                a[mt] = *(const bf16x8*)&xs[mt * 16 + cl][k0];
#pragma unroll
            for (int nt = 0; nt < 4; ++nt)
                bb[nt] = *(const bf16x8*)(w1base + (size_t)(nt * 16 + cl) * KDIM + k0);
#pragma unroll
            for (int mt = 0; mt < 4; ++mt)
#pragma unroll
                for (int nt = 0; nt < 4; ++nt)
                    acc[mt][nt] = __builtin_amdgcn_mfma_f32_16x16x32_bf16(
                        a[mt], bb[nt], acc[mt][nt], 0, 0, 0);
        }
        __builtin_amdgcn_s_setprio(0);

        __syncthreads();   // B2: all xs reads done -> region may be overwritten

        // ---- epilogue 1: +b1, relu, bf16 -> hs (overlays xs) ----
#pragma unroll
        for (int nt = 0; nt < 4; ++nt) {
#pragma unroll
            for (int mt = 0; mt < 4; ++mt) {
#pragma unroll
                for (int r = 0; r < 4; ++r) {
                    float v = acc[mt][nt][r] + bias1[nt];
                    v = v > 0.f ? v : 0.f;
                    hs[mt * 16 + q * 4 + r][wn0 + nt * 16 + cl] = (bf16)v;
                }
            }
        }
        __syncthreads();   // B3: hs ready

        // ---- layer 2: wave owns M rows [16w, 16w+16), K=256 ----
        f32x4 acc2[4] = {};
        __builtin_amdgcn_s_setprio(1);
#pragma unroll
        for (int ks = 0; ks < 8; ++ks) {
            const int k0 = ks * 32 + q * 8;
            bf16x8 a = *(const bf16x8*)&hs[m0 + cl][k0];
#pragma unroll
            for (int nt = 0; nt < 4; ++nt) {
                bf16x8 bb = *(const bf16x8*)(W2T + (size_t)(nt * 16 + cl) * HDIM + k0);
                acc2[nt] = __builtin_amdgcn_mfma_f32_16x16x32_bf16(a, bb, acc2[nt], 0, 0, 0);
            }
        }
        __builtin_amdgcn_s_setprio(0);

        // ---- staging loads for tile t+1 (after all weight loads; in-order
        //      vmcnt -> weight waits never queue behind these) ----
        const bool hasnext = (itn < ntiles);
        f32x4 dr2[4], sr2[4], ur2[4];
        if (hasnext) {
            const size_t tb = (size_t)itn * 1024;
#pragma unroll
            for (int j = 0; j < 4; ++j) {
                const int g = j * 256 + tid;
                const int en = itn * 64 + (g >> 4);
                if (en < E) {
                    dr2[j] = ((const f32x4*)destf)[tb + g];
                    sr2[j] = ((const f32x4*)srcf)[tb + g];
                } else { dr2[j] = zero4; sr2[j] = zero4; }
            }
            const int en = itn * 64 + row;
            if (en < E) {
                const f32x4* up = (const f32x4*)(u + (size_t)bn * 64 + c0);
#pragma unroll
                for (int i = 0; i < 4; ++i) ur2[i] = up[i];
            } else {
#pragma unroll
                for (int i = 0; i < 4; ++i) ur2[i] = zero4;
            }
        }
        int itnn = itn + stride;
        int bnn  = 0;
        if (itnn < ntiles) {
            int enn = itnn * 64 + row;
            if (enn < E) bnn = batch[enn];
        }

        // ---- epilogue 2: +b2 -> outs (wave-private band of the hs region;
        //      own-wave hs reads completed above, other waves never touch
        //      band w in this phase) ----
#pragma unroll
        for (int nt = 0; nt < 4; ++nt)
#pragma unroll
            for (int r = 0; r < 4; ++r)
                outs[m0 + q * 4 + r][nt * 16 + cl] = acc2[nt][r] + bias2[nt];

        // full-line stores: 4 consecutive 256B rows = 1KB contiguous / instr
#pragma unroll
        for (int p = 0; p < 4; ++p) {
            const int orow = m0 + p * 4 + q;
            const int ee   = e0 + orow;
            if (ee < E) {
                f32x4 v = *(const f32x4*)&outs[orow][cl * 4];
                *(f32x4*)(out + (size_t)ee * 64 + cl * 4) = v;
            }
        }

        if (!hasnext) break;

        __syncthreads();   // B4: hs/outs phase done -> region free for staging

        it = itn; itn = itnn; bn = bnn;
#pragma unroll
        for (int i = 0; i < 4; ++i) { dr[i] = dr2[i]; sr[i] = sr2[i]; ur[i] = ur2[i]; }
    }
}

extern "C" void kernel_launch(void* const* d_in, const int* in_sizes, int n_in,
                              void* d_out, int out_size, void* d_ws, size_t ws_size,
                              hipStream_t stream)
{
    const float* srcf  = (const float*)d_in[0];
    const float* destf = (const float*)d_in[1];
    // d_in[2] = edge_attr: UNUSED by reference — never touched.
    const float* u     = (const float*)d_in[3];
    const int*   batch = (const int*)d_in[4];
    const float* W1    = (const float*)d_in[5];
    const float* b1    = (const float*)d_in[6];
    const float* W2    = (const float*)d_in[7];
    const float* b2    = (const float*)d_in[8];
    float* out = (float*)d_out;

    const int E = in_sizes[0] / 64;   // src is [E, 64]

    bf16* W1T = (bf16*)d_ws;                  // 256*192 bf16 = 98304 B
    bf16* W2T = W1T + KDIM * HDIM;            // 64*256  bf16 = 32768 B

    prep_weights<<<(KDIM * HDIM + HDIM * NOUT) / 256, 256, 0, stream>>>(W1, W2, W1T, W2T);

    const int ntiles = (E + 63) / 64;
    const int nblocks = ntiles < 1024 ? ntiles : 1024;   // 4 blocks/CU resident
    edge_mlp<<<nblocks, 256, 0, stream>>>(srcf, destf, u, batch,
                                          W1T, b1, W2T, b2, out, E);
}

// Round 4
// 410.710 us; speedup vs baseline: 2.1878x; 2.1878x over previous
//
#include <hip/hip_runtime.h>

typedef __bf16 bf16;
typedef __bf16 bf16x8 __attribute__((ext_vector_type(8)));
typedef __bf16 bf16x4 __attribute__((ext_vector_type(4)));
typedef float  f32x4  __attribute__((ext_vector_type(4)));

// Problem constants: FX=64, FU=64, f_in=192, H=256, FE_OUT=64
#define KDIM 192
#define HDIM 256
#define NOUT 64

// ---------------------------------------------------------------------------
// Prep: weights -> bf16 in FRAG-NATIVE order so the GEMM kernel's LDS reads
// are (uniform base + lane*16B).
// W1L frag (ntg 0..15, ks 0..5, q 0..3, cl 0..15), elem j0..7:
//     = W1[(ks*32+q*8+j)][ntg*16+cl]          (49152 bf16 = 98304 B)
// W2L frag (nq 0..3, ks 0..7, q, cl), elem j: = W2[(ks*32+q*8+j)][nq*16+cl]
//                                              (16384 bf16 = 32768 B)
// ---------------------------------------------------------------------------
__global__ __launch_bounds__(256) void prep_weights(
    const float* __restrict__ W1, const float* __restrict__ W2,
    bf16* __restrict__ W1L, bf16* __restrict__ W2L)
{
    int gid = blockIdx.x * 256 + threadIdx.x;        // 65536 total
    if (gid < KDIM * HDIM) {
        int j = gid & 7, f = gid >> 3;
        int cl = f & 15, q = (f >> 4) & 3, t = f >> 6;   // t = ntg*6+ks
        int ks = t % 6, ntg = t / 6;
        W1L[gid] = (bf16)W1[(ks * 32 + q * 8 + j) * HDIM + ntg * 16 + cl];
    } else {
        int g2 = gid - KDIM * HDIM;                  // 0..16383
        int j = g2 & 7, f = g2 >> 3;
        int cl = f & 15, q = (f >> 4) & 3, t = f >> 6;   // t = nq*8+ks
        int ks = t & 7, nq = t >> 3;
        W2L[g2] = (bf16)W2[(ks * 32 + q * 8 + j) * NOUT + nq * 16 + cl];
    }
}

// ---------------------------------------------------------------------------
// Round-4: WEIGHTS IN LDS. Four rounds of evidence: all pipes idle, BW stuck
// at 3.1 TB/s, FETCH excess ~390MB invariant to access patterns, 46K cyc per
// block-tile vs ~3K of work => serialized L2-latency chains on the ~56 global
// weight loads re-issued EVERY tile. Fix: block loads all weights (131072 B,
// frag-native) into LDS once; per-tile weight access becomes pipelined
// ds_read_b128 (~12cyc). LDS = 131072 + 32768 (xs/hs/outs overlay region)
// = 163840 B = exactly 160 KiB. 512 threads / 8 waves, 1 block/CU.
//   L1: wave owns N cols [32w,32w+32) (ntg = 2w+nt), all 64 rows.
//   L2: wave owns out tile (mq = w&3, nq = (w>>2)*2+s).
//   hs: [64][256] bf16, XOR-swizzled byte ^= (row&7)<<4 (else 16-way bank
//       conflict on the stride-512B column reads).
// Barriers: stage|B1|prefetch+L1|B2|epi1|B3|L2|B4|epi2|B5|stores|B6.
// Streaming prefetch issued after B1 -> compiler's vmcnt(0) drain lands at
// B2, one full L1 later (no global weight loads exist to queue behind it).
// ---------------------------------------------------------------------------
__global__ __launch_bounds__(512, 2) void edge_mlp(
    const float* __restrict__ srcf, const float* __restrict__ destf,
    const float* __restrict__ u,    const int* __restrict__ batch,
    const bf16* __restrict__ WL,    const float* __restrict__ b1,
    const float* __restrict__ b2,   float* __restrict__ out, int E)
{
    // [region 32768][W1L 98304][W2L 32768] = 163840 B
    __shared__ __align__(16) unsigned char smem[163840];
    bf16 (*xs)[200]  = (bf16 (*)[200])smem;            // 25600 B, in region
    unsigned char* hsb = smem;                         // hs 64 x 512B, swz
    float (*outs)[64] = (float (*)[64])smem;           // 16384 B, in region
    unsigned char* w1l = smem + 32768;
    unsigned char* w2l = smem + 32768 + 98304;

    const int tid  = threadIdx.x;                     // 0..511
    const int wave = tid >> 6;                        // 0..7
    const int lane = tid & 63;
    const int q    = lane >> 4;                       // 0..3
    const int cl   = lane & 15;                       // 0..15

    // staging coords: f32x4 #(j*512+tid) of the 64x64 f32 tile
    const int r0 = tid >> 4;          // row for j=0 (0..31); j=1 adds 32
    const int cp = tid & 15;          // f32x4 slot in row
    // u-gather coords
    const int urow = tid >> 3;        // 0..63
    const int uc0  = (tid & 7) * 8;   // 8 floats per thread

    const int ntiles = (E + 63) >> 6;
    const int stride = gridDim.x;

    int it = blockIdx.x;
    if (it >= ntiles) return;

    // ---- weight preamble: 131072 B global -> LDS (once) ----
    {
        const int4* wsrc = (const int4*)WL;
        int4* wdst = (int4*)w1l;
#pragma unroll
        for (int i = 0; i < 16; ++i)
            wdst[i * 512 + tid] = wsrc[i * 512 + tid];
    }

    // L2 partition
    const int mq = wave & 3;
    const int np = wave >> 2;

    float bias1[2], bias2[2];
#pragma unroll
    for (int nt = 0; nt < 2; ++nt) {
        bias1[nt] = b1[wave * 32 + nt * 16 + cl];
        bias2[nt] = b2[(np * 2 + nt) * 16 + cl];
    }

    f32x4 dr[2], sr[2], ur[2];
    const f32x4 zero4 = {0.f, 0.f, 0.f, 0.f};

    // ---- preamble: tile(it) streaming -> regs ----
    {
        const size_t tb = (size_t)it * 1024;
#pragma unroll
        for (int j = 0; j < 2; ++j) {
            const int e = it * 64 + j * 32 + r0;
            if (e < E) {
                dr[j] = ((const f32x4*)destf)[tb + j * 512 + tid];
                sr[j] = ((const f32x4*)srcf)[tb + j * 512 + tid];
            } else { dr[j] = zero4; sr[j] = zero4; }
        }
        const int e = it * 64 + urow;
        if (e < E) {
            const int b = batch[e];
            const f32x4* up = (const f32x4*)(u + (size_t)b * 64 + uc0);
            ur[0] = up[0]; ur[1] = up[1];
        } else { ur[0] = zero4; ur[1] = zero4; }
    }
    int itn = it + stride;
    int bn  = 0;
    if (itn < ntiles) {
        int en = itn * 64 + urow;
        if (en < E) bn = batch[en];
    }

    while (true) {
        const int e0 = it * 64;

        // ---- stage xs (fp32 -> bf16) into region ----
#pragma unroll
        for (int j = 0; j < 2; ++j) {
            const int r = j * 32 + r0;
            bf16x4 db = { (bf16)dr[j].x, (bf16)dr[j].y, (bf16)dr[j].z, (bf16)dr[j].w };
            bf16x4 sb = { (bf16)sr[j].x, (bf16)sr[j].y, (bf16)sr[j].z, (bf16)sr[j].w };
            *(bf16x4*)&xs[r][cp * 4]      = db;
            *(bf16x4*)&xs[r][64 + cp * 4] = sb;
        }
#pragma unroll
        for (int i = 0; i < 2; ++i) {
            bf16x4 ub = { (bf16)ur[i].x, (bf16)ur[i].y, (bf16)ur[i].z, (bf16)ur[i].w };
            *(bf16x4*)&xs[urow][128 + uc0 + i * 4] = ub;
        }

        __syncthreads();   // B1: xs ready (also weight LDS visible on iter 0)

        // ---- prefetch tile t+1 (drains at B2, one full L1 later) ----
        const bool hasnext = (itn < ntiles);
        f32x4 dr2[2], sr2[2], ur2[2];
        if (hasnext) {
            const size_t tb = (size_t)itn * 1024;
#pragma unroll
            for (int j = 0; j < 2; ++j) {
                const int en = itn * 64 + j * 32 + r0;
                if (en < E) {
                    dr2[j] = ((const f32x4*)destf)[tb + j * 512 + tid];
                    sr2[j] = ((const f32x4*)srcf)[tb + j * 512 + tid];
                } else { dr2[j] = zero4; sr2[j] = zero4; }
            }
            const int en = itn * 64 + urow;
            if (en < E) {
                const f32x4* up = (const f32x4*)(u + (size_t)bn * 64 + uc0);
                ur2[0] = up[0]; ur2[1] = up[1];
            } else { ur2[0] = zero4; ur2[1] = zero4; }
        }
        int itnn = itn + stride;
        int bnn  = 0;
        if (itnn < ntiles) {
            int enn = itnn * 64 + urow;
            if (enn < E) bnn = batch[enn];
        }

        // ---- layer 1: all-LDS operands ----
        f32x4 acc[4][2] = {};
        const unsigned char* w1p = w1l + (size_t)(2 * wave) * 6144 + lane * 16;
        __builtin_amdgcn_s_setprio(1);
#pragma unroll
        for (int ks = 0; ks < 6; ++ks) {
            const int k0 = ks * 32 + q * 8;
            bf16x8 a[4], bb[2];
#pragma unroll
            for (int mt = 0; mt < 4; ++mt)
                a[mt] = *(const bf16x8*)&xs[mt * 16 + cl][k0];
#pragma unroll
            for (int nt = 0; nt < 2; ++nt)
                bb[nt] = *(const bf16x8*)(w1p + nt * 6144 + ks * 1024);
#pragma unroll
            for (int mt = 0; mt < 4; ++mt)
#pragma unroll
                for (int nt = 0; nt < 2; ++nt)
                    acc[mt][nt] = __builtin_amdgcn_mfma_f32_16x16x32_bf16(
                        a[mt], bb[nt], acc[mt][nt], 0, 0, 0);
        }
        __builtin_amdgcn_s_setprio(0);

        __syncthreads();   // B2: xs reads done; prefetch drained here

        // ---- epilogue 1: +b1, relu -> hs (XOR-swizzled, overlays region) ----
#pragma unroll
        for (int nt = 0; nt < 2; ++nt) {
            const int col2 = (wave * 32 + nt * 16 + cl) * 2;
#pragma unroll
            for (int mt = 0; mt < 4; ++mt) {
#pragma unroll
                for (int r = 0; r < 4; ++r) {
                    const int row = mt * 16 + q * 4 + r;
                    float v = acc[mt][nt][r] + bias1[nt];
                    v = v > 0.f ? v : 0.f;
                    *(bf16*)(hsb + row * 512 + (col2 ^ ((row & 7) << 4))) = (bf16)v;
                }
            }
        }
        __syncthreads();   // B3: hs ready

        // ---- layer 2: all-LDS operands ----
        f32x4 acc2[2] = {};
        const unsigned char* w2p = w2l + (size_t)(np * 2) * 8192 + lane * 16;
        const int arow = mq * 16 + cl;
        const unsigned char* hrow = hsb + arow * 512;
        const int aswz = (arow & 7) << 4;
        __builtin_amdgcn_s_setprio(1);
#pragma unroll
        for (int ks = 0; ks < 8; ++ks) {
            bf16x8 a = *(const bf16x8*)(hrow + ((ks * 64 + q * 16) ^ aswz));
#pragma unroll
            for (int s = 0; s < 2; ++s) {
                bf16x8 bb = *(const bf16x8*)(w2p + s * 8192 + ks * 1024);
                acc2[s] = __builtin_amdgcn_mfma_f32_16x16x32_bf16(a, bb, acc2[s], 0, 0, 0);
            }
        }
        __builtin_amdgcn_s_setprio(0);

        __syncthreads();   // B4: hs reads done; region free

        // ---- epilogue 2: +b2 -> outs (f32, region reuse) ----
#pragma unroll
        for (int s = 0; s < 2; ++s)
#pragma unroll
            for (int r = 0; r < 4; ++r)
                outs[mq * 16 + q * 4 + r][(np * 2 + s) * 16 + cl] = acc2[s][r] + bias2[s];

        __syncthreads();   // B5: outs ready

        // ---- full-line stores: 1KB contiguous per wave instruction ----
#pragma unroll
        for (int j = 0; j < 2; ++j) {
            const int orow = j * 32 + r0;
            const int ee   = e0 + orow;
            if (ee < E) {
                f32x4 v = *(const f32x4*)&outs[orow][cp * 4];
                *(f32x4*)(out + (size_t)ee * 64 + cp * 4) = v;
            }
        }

        if (!hasnext) break;

        __syncthreads();   // B6: outs reads done; region free for next stage

        it = itn; itn = itnn; bn = bnn;
#pragma unroll
        for (int i = 0; i < 2; ++i) { dr[i] = dr2[i]; sr[i] = sr2[i]; ur[i] = ur2[i]; }
    }
}

extern "C" void kernel_launch(void* const* d_in, const int* in_sizes, int n_in,
                              void* d_out, int out_size, void* d_ws, size_t ws_size,
                              hipStream_t stream)
{
    const float* srcf  = (const float*)d_in[0];
    const float* destf = (const float*)d_in[1];
    // d_in[2] = edge_attr: UNUSED by reference — never touched.
    const float* u     = (const float*)d_in[3];
    const int*   batch = (const int*)d_in[4];
    const float* W1    = (const float*)d_in[5];
    const float* b1    = (const float*)d_in[6];
    const float* W2    = (const float*)d_in[7];
    const float* b2    = (const float*)d_in[8];
    float* out = (float*)d_out;

    const int E = in_sizes[0] / 64;   // src is [E, 64]

    bf16* W1L = (bf16*)d_ws;                  // 49152 bf16 = 98304 B
    bf16* W2L = W1L + KDIM * HDIM;            // 16384 bf16 = 32768 B (contig)

    prep_weights<<<(KDIM * HDIM + HDIM * NOUT) / 256, 256, 0, stream>>>(W1, W2, W1L, W2L);

    const int ntiles = (E + 63) / 64;
    const int nblocks = ntiles < 256 ? ntiles : 256;   // 1 block/CU, 8 waves
    edge_mlp<<<nblocks, 512, 0, stream>>>(srcf, destf, u, batch,
                                          (const bf16*)W1L, b1, b2, out, E);
}